// Round 16
// baseline (1077.555 us; speedup 1.0000x reference)
//
#include <hip/hip_runtime.h>
#include <math.h>

// Net: ConvLSTM(32)->pool->ConvLSTM(48)->pool->conv3+ELU->conv4(1x1)+ELU->conv5(1x1)
// B=8, T=32, H=8, W=256, F1=32, F2=48, F3=256, F4=128, NNOTE=88
// R16: R15 pair-fusion with the NaN bug fixed: stage the FULL raw[5][36][40]
//      tile (ci 33..39 zeroed) so B-fragment reads at ci0=32 never touch
//      uninitialized LDS (0 x NaN-garbage poisoned R15).

#define DEVINL static __device__ __forceinline__
typedef __attribute__((ext_vector_type(8))) short short8;
typedef __attribute__((ext_vector_type(4))) float f32x4;

#define PLANE_W3 2359296

DEVINL float sigm(float x) { return 1.0f / (1.0f + __expf(-x)); }
DEVINL float tanh_fast(float x) { return 1.0f - 2.0f / (__expf(2.0f * x) + 1.0f); }
DEVINL float elu(float x) { return x > 0.0f ? x : expm1f(x); }
DEVINL unsigned short bf16_rne(float v) {
    unsigned u = __float_as_uint(v);
    unsigned r = (u + 0x7FFF + ((u >> 16) & 1)) >> 16;
    return (unsigned short)r;
}
DEVINL float bf16_to_f(unsigned short h) { return __uint_as_float(((unsigned)h) << 16); }
DEVINL unsigned pack_hl(float v) {
    unsigned short hi = bf16_rne(v);
    unsigned short lo = bf16_rne(v - bf16_to_f(hi));
    return (unsigned)hi | ((unsigned)lo << 16);
}
DEVINL float upk(unsigned u) {
    return __uint_as_float(u << 16) + __uint_as_float(u & 0xffff0000u);
}

// ---------------- LSTM2 step body (R13/R14 logic, LDS passed in) ------------
DEVINL void lstm2_body(
    int xq, int y, int b, int t,
    const unsigned* __restrict__ p1pk, const unsigned short* __restrict__ w2F,
    const float* __restrict__ b2,
    const unsigned* __restrict__ hprev, const unsigned* __restrict__ hpool,
    float* __restrict__ c2, unsigned* __restrict__ hout,
    unsigned short* __restrict__ p2hi, unsigned short* __restrict__ p2lo,
    const unsigned* __restrict__ h30, const unsigned* __restrict__ h31,
    unsigned short* sChi, unsigned short* sClo)
{
    const int x0 = xq * 16;
    const int tid = threadIdx.x;

    if (((t & 1) == 0) && t >= 2 && y < 2) {
        int tp = (t >> 1) - 1;
        for (int e = tid; e < 48 * 8; e += 256) {
            int f = e >> 3, xl = e & 7;
            int xp = xq * 8 + xl;
            int g0 = ((b * 48 + f) * 4 + y * 2) * 128 + xp * 2;
            float m = fmaxf(fmaxf(upk(hpool[g0]), upk(hpool[g0 + 1])),
                            fmaxf(upk(hpool[g0 + 128]), upk(hpool[g0 + 129])));
            m = fmaxf(m, fmaxf(fmaxf(upk(hprev[g0]), upk(hprev[g0 + 1])),
                               fmaxf(upk(hprev[g0 + 128]), upk(hprev[g0 + 129]))));
            int pi = ((b * 48 + f) * 16 + tp * 2 + y) * 64 + xp;
            unsigned pm = pack_hl(m);
            p2hi[pi] = (unsigned short)pm;
            p2lo[pi] = (unsigned short)(pm >> 16);
        }
    }

    for (int idx = tid; idx < 80 * 54; idx += 256) {
        int ci = idx / 54, rem = idx % 54;
        int dy = rem / 18, lx = rem % 18;
        int gy = y + dy - 1, gx = x0 + lx - 1;
        unsigned u = 0;
        if (gy >= 0 && gy < 4 && gx >= 0 && gx < 128) {
            if (ci < 32) {
                if (t == 15) {
                    int b0 = ((b * 32 + ci) * 8 + gy * 2) * 256 + gx * 2;
                    float m = upk(h30[b0]);
                    m = fmaxf(m, upk(h30[b0 + 1]));
                    m = fmaxf(m, upk(h30[b0 + 256]));
                    m = fmaxf(m, upk(h30[b0 + 257]));
                    m = fmaxf(m, upk(h31[b0]));
                    m = fmaxf(m, upk(h31[b0 + 1]));
                    m = fmaxf(m, upk(h31[b0 + 256]));
                    m = fmaxf(m, upk(h31[b0 + 257]));
                    u = pack_hl(m);
                } else {
                    u = p1pk[(((b * 32 + ci) * 16 + t) * 4 + gy) * 128 + gx];
                }
            } else if (t > 0) {
                u = hprev[((b * 48 + (ci - 32)) * 4 + gy) * 128 + gx];
            }
        }
        int k = ci * 3 + dy;
        int a16 = lx * 256 + (((k >> 3) ^ (lx & 15)) << 3) + (k & 7);
        sChi[a16] = (unsigned short)u;
        sClo[a16] = (unsigned short)(u >> 16);
    }
    for (int e = tid; e < 18 * 16; e += 256) {
        int lx = e >> 4, k = 240 + (e & 15);
        int a16 = lx * 256 + (((k >> 3) ^ (lx & 15)) << 3) + (k & 7);
        sChi[a16] = 0;
        sClo[a16] = 0;
    }
    __syncthreads();

    const int l = tid & 63;
    const int wv = __builtin_amdgcn_readfirstlane(tid >> 6);
    const int ln = l & 15, kg = l >> 4;
    f32x4 acc[3] = {{0.f,0.f,0.f,0.f},{0.f,0.f,0.f,0.f},{0.f,0.f,0.f,0.f}};

#pragma unroll
    for (int kk = 0; kk < 8; ++kk) {
        short8 bh[3], bl[3];
#pragma unroll
        for (int dx = 0; dx < 3; ++dx) {
            int lx = ln + dx;
            int boff = lx * 256 + ((((kk << 2) + kg) ^ (lx & 15)) << 3);
            bh[dx] = *(const short8*)&sChi[boff];
            bl[dx] = *(const short8*)&sClo[boff];
        }
#pragma unroll
        for (int j = 0; j < 3; ++j) {
            int mt = wv * 3 + j;
#pragma unroll
            for (int dx = 0; dx < 3; ++dx) {
                int aoff = ((((dx * 12 + mt) * 8 + kk) * 4 + kg) * 16 + ln) * 8;
                short8 ah = *(const short8*)&w2F[aoff];
                acc[j] = __builtin_amdgcn_mfma_f32_16x16x32_bf16(ah, bl[dx], acc[j], 0, 0, 0);
                acc[j] = __builtin_amdgcn_mfma_f32_16x16x32_bf16(ah, bh[dx], acc[j], 0, 0, 0);
            }
        }
    }

    const int x = x0 + ln;
#pragma unroll
    for (int j = 0; j < 3; ++j) {
        int mt = wv * 3 + j;
        int f = mt * 4 + kg;
        float zi = acc[j][0] + b2[f];
        float zf = acc[j][1] + b2[48 + f];
        float zg = acc[j][2] + b2[96 + f];
        float zo = acc[j][3] + b2[144 + f];
        int gidx = ((b * 48 + f) * 4 + y) * 128 + x;
        float cv = (t > 0) ? c2[gidx] : 0.0f;
        float cn = sigm(zf) * cv + sigm(zi) * tanh_fast(zg);
        c2[gidx] = cn;
        hout[gidx] = pack_hl(sigm(zo) * tanh_fast(cn));
    }
}

// ---------------- fused LSTM1 pair body ----------------
// Block (xq 8, y 8, b 8) = 512; 4 waves = (mh 2) x (nh 2).
// raw[frow 5][lx 36][ci 40] hi/lo: K = dy*40+ci ordering (chunks of 8).
// t0: 3 rows x 34 cols; t1: 1 row x 32 cols. h(t0)/c(t0) relayed in LDS.
DEVINL void lstm1_pair(
    int xq, int y, int b, int j, int poolIdx,
    const float* __restrict__ x, const unsigned short* __restrict__ w1F,
    const float* __restrict__ b1,
    const unsigned* __restrict__ hprev,                      // h(2j-1)
    const unsigned* __restrict__ hA, const unsigned* __restrict__ hB, // pool pair
    unsigned* __restrict__ hC, unsigned* __restrict__ hD,    // h(2j), h(2j+1)
    const float* __restrict__ cPrev, float* __restrict__ cOut,
    unsigned* __restrict__ p1pk,
    unsigned short* rawHi, unsigned short* rawLo, float* cLds)
{
    const int x0 = xq * 32;
    const int t0 = 2 * j;
    const int tid = threadIdx.x;

    // pool previous pair (h(2j-2), h(2j-1)) -> p1[j-1]; 1 output/thread
    if (j >= 1) {
        int idx = poolIdx * 256 + tid;
        int xp = idx & 127, q1 = idx >> 7;
        int yp = q1 & 3, q2 = q1 >> 2;
        int f = q2 & 31, bb = q2 >> 5;
        int base = ((bb * 32 + f) * 8 + yp * 2) * 256 + xp * 2;
        float m = upk(hA[base]);
        m = fmaxf(m, upk(hA[base + 1]));
        m = fmaxf(m, upk(hA[base + 256]));
        m = fmaxf(m, upk(hA[base + 257]));
        m = fmaxf(m, upk(hB[base]));
        m = fmaxf(m, upk(hB[base + 1]));
        m = fmaxf(m, upk(hB[base + 256]));
        m = fmaxf(m, upk(hB[base + 257]));
        p1pk[(((bb * 32 + f) * 16 + (j - 1)) * 4 + yp) * 128 + xp] = pack_hl(m);
    }

    // stage t0: FULL raw[frow][lx][ci 0..39] (ci>=33 zero) -- R15 NaN fix
    for (int e = tid; e < 7200; e += 256) {
        int lx = e % 36, r2 = e / 36;
        int frow = r2 % 5, ci = r2 / 5;
        int gy = y - 2 + frow, gx = x0 - 2 + lx;
        unsigned u = 0;
        if (ci < 33 && gy >= 0 && gy < 8 && gx >= 0 && gx < 256) {
            if (ci == 0) u = pack_hl(x[((b * 32 + t0) * 8 + gy) * 256 + gx]);
            else if (j > 0) u = hprev[((b * 32 + ci - 1) * 8 + gy) * 256 + gx];
        }
        int a = (frow * 36 + lx) * 40 + ci;
        rawHi[a] = (unsigned short)u;
        rawLo[a] = (unsigned short)(u >> 16);
    }
    __syncthreads();

    const int l = tid & 63;
    const int wv = __builtin_amdgcn_readfirstlane(tid >> 6);
    const int mh = wv >> 1, nh = wv & 1;
    const int ln = l & 15, kg = l >> 4;
    const int ntB = nh * 4;

    f32x4 acc[5][4];
#pragma unroll
    for (int i = 0; i < 5; ++i)
#pragma unroll
        for (int m2 = 0; m2 < 4; ++m2) acc[i][m2] = (f32x4){0.f, 0.f, 0.f, 0.f};

#pragma unroll
    for (int kk = 0; kk < 4; ++kk) {
        int q = kk * 4 + kg;
        int dy0 = (q >= 15) ? 2 : q / 5;   // q==15: A is zero; keep addr in-bounds
        int ci0 = (q % 5) * 8;
#pragma unroll
        for (int dx = 0; dx < 3; ++dx) {
            short8 bh[5], bl[5];
#pragma unroll
            for (int ntl = 0; ntl < 5; ++ntl) {
                int nt = ntB + ntl;
                int r = nt / 3, ct = nt - r * 3;
                int lx = ct * 16 + ln + dx;
                lx = (lx > 35) ? 35 : lx;  // garbage cols discarded in epilogue
                int a = ((r + dy0) * 36 + lx) * 40 + ci0;
                bh[ntl] = *(const short8*)&rawHi[a];
                bl[ntl] = *(const short8*)&rawLo[a];
            }
#pragma unroll
            for (int mtl = 0; mtl < 4; ++mtl) {
                int aoff = ((((dx * 8 + mh * 4 + mtl) * 4 + kk) * 4 + kg) * 16 + ln) * 8;
                short8 ah = *(const short8*)&w1F[aoff];
#pragma unroll
                for (int ntl = 0; ntl < 5; ++ntl) {
                    acc[ntl][mtl] = __builtin_amdgcn_mfma_f32_16x16x32_bf16(ah, bl[ntl], acc[ntl][mtl], 0, 0, 0);
                    acc[ntl][mtl] = __builtin_amdgcn_mfma_f32_16x16x32_bf16(ah, bh[ntl], acc[ntl][mtl], 0, 0, 0);
                }
            }
        }
    }
    __syncthreads();   // all t0 reads done before raw is overwritten

    // t0 epilogue: gates; h(t0) -> raw (frames 1..3, ci 1..32) + hC center row;
    // c(t0) center row -> cLds
#pragma unroll
    for (int mtl = 0; mtl < 4; ++mtl) {
        const int f = (mh * 4 + mtl) * 4 + kg;
        const float bi = b1[f], bff = b1[32 + f], bg = b1[64 + f], bo = b1[96 + f];
#pragma unroll
        for (int ntl = 0; ntl < 5; ++ntl) {
            int nt = ntB + ntl;
            int r = nt / 3, ct = nt - r * 3;
            int cp = ct * 16 + ln;
            if (cp < 34) {
                int crel = cp - 1;
                int grow = y - 1 + r;
                int col = x0 + crel;
                float hv = 0.0f, cn = 0.0f;
                if (grow >= 0 && grow < 8 && col >= 0 && col < 256) {
                    f32x4 a = acc[ntl][mtl];
                    float zi = a[0] + bi, zf = a[1] + bff;
                    float zg = a[2] + bg, zo = a[3] + bo;
                    float cv = (j > 0) ? cPrev[((b * 32 + f) * 8 + grow) * 256 + col] : 0.0f;
                    cn = sigm(zf) * cv + sigm(zi) * tanh_fast(zg);
                    hv = sigm(zo) * tanh_fast(cn);
                }
                unsigned pk = pack_hl(hv);
                int a2 = ((r + 1) * 36 + (crel + 2)) * 40 + 1 + f;
                rawHi[a2] = (unsigned short)pk;
                rawLo[a2] = (unsigned short)(pk >> 16);
                if (r == 1 && crel >= 0 && crel < 32) {
                    cLds[f * 32 + crel] = cn;
                    hC[((b * 32 + f) * 8 + y) * 256 + col] = pk;
                }
            }
        }
    }

    // stage x(t1) into raw frames 1..3, lx 1..34, ci 0
    for (int e = tid; e < 102; e += 256) {
        int lx = e % 34 + 1, frow = e / 34 + 1;
        int gy = y - 2 + frow, gx = x0 - 2 + lx;
        unsigned u = 0;
        if (gy >= 0 && gy < 8 && gx >= 0 && gx < 256)
            u = pack_hl(x[((b * 32 + t0 + 1) * 8 + gy) * 256 + gx]);
        int a = (frow * 36 + lx) * 40;
        rawHi[a] = (unsigned short)u;
        rawLo[a] = (unsigned short)(u >> 16);
    }
    __syncthreads();

    // t1 MFMA: interior row y, cols x0 + nh*16 + ln
    f32x4 acc2[4];
#pragma unroll
    for (int m2 = 0; m2 < 4; ++m2) acc2[m2] = (f32x4){0.f, 0.f, 0.f, 0.f};
#pragma unroll
    for (int kk = 0; kk < 4; ++kk) {
        int q = kk * 4 + kg;
        int dy0 = q / 5;                // q==15 -> frame 4 (A zero, finite data)
        int ci0 = (q % 5) * 8;
#pragma unroll
        for (int dx = 0; dx < 3; ++dx) {
            int lx = nh * 16 + ln + dx + 1;
            int a = ((1 + dy0) * 36 + lx) * 40 + ci0;
            short8 bh2 = *(const short8*)&rawHi[a];
            short8 bl2 = *(const short8*)&rawLo[a];
#pragma unroll
            for (int mtl = 0; mtl < 4; ++mtl) {
                int aoff = ((((dx * 8 + mh * 4 + mtl) * 4 + kk) * 4 + kg) * 16 + ln) * 8;
                short8 ah = *(const short8*)&w1F[aoff];
                acc2[mtl] = __builtin_amdgcn_mfma_f32_16x16x32_bf16(ah, bl2, acc2[mtl], 0, 0, 0);
                acc2[mtl] = __builtin_amdgcn_mfma_f32_16x16x32_bf16(ah, bh2, acc2[mtl], 0, 0, 0);
            }
        }
    }

    // t1 epilogue
#pragma unroll
    for (int mtl = 0; mtl < 4; ++mtl) {
        const int f = (mh * 4 + mtl) * 4 + kg;
        int col = x0 + nh * 16 + ln;
        f32x4 a = acc2[mtl];
        float zi = a[0] + b1[f], zf = a[1] + b1[32 + f];
        float zg = a[2] + b1[64 + f], zo = a[3] + b1[96 + f];
        float cv = cLds[f * 32 + nh * 16 + ln];
        float cn = sigm(zf) * cv + sigm(zi) * tanh_fast(zg);
        int g = ((b * 32 + f) * 8 + y) * 256 + col;
        cOut[g] = cn;
        hD[g] = pack_hl(sigm(zo) * tanh_fast(cn));
    }
}

// ---------------- fused kernel: lstm1 pair + embedded lstm2 ----------------
__global__ __launch_bounds__(256) void fused_k(
    const float* __restrict__ x, const unsigned short* __restrict__ w1F,
    const float* __restrict__ b1,
    const unsigned* __restrict__ hprev, const unsigned* __restrict__ hA,
    const unsigned* __restrict__ hB,
    unsigned* __restrict__ hC, unsigned* __restrict__ hD,
    const float* __restrict__ cPrev, float* __restrict__ cOut,
    unsigned* __restrict__ p1pk,
    const unsigned short* __restrict__ w2F, const float* __restrict__ b2,
    const unsigned* __restrict__ h2prev, const unsigned* __restrict__ h2pool,
    unsigned* __restrict__ h2out, float* __restrict__ c2,
    unsigned short* __restrict__ p2hi, unsigned short* __restrict__ p2lo,
    int j, int t2)
{
    __shared__ __align__(16) unsigned char lds[45184];
    int bid = blockIdx.x;
    if (t2 >= 0) {
        if (bid < 256) {
            lstm2_body(bid & 7, (bid >> 3) & 3, bid >> 5, t2,
                       p1pk, w2F, b2, h2prev, h2pool, c2, h2out, p2hi, p2lo,
                       hC, hC,
                       (unsigned short*)lds, (unsigned short*)(lds + 9216));
            return;
        }
        bid -= 256;
    }
    lstm1_pair(bid & 7, (bid >> 3) & 7, bid >> 6, j, bid,
               x, w1F, b1, hprev, hA, hB, hC, hD, cPrev, cOut, p1pk,
               (unsigned short*)lds, (unsigned short*)(lds + 14400),
               (float*)(lds + 28800));
}

// ---------------- standalone lstm2 (tp=14 and tp=15 with pool1 fold) --------
__global__ __launch_bounds__(256) void lstm2_k(
    const unsigned* __restrict__ p1pk, const unsigned short* __restrict__ w2F,
    const float* __restrict__ b2,
    const unsigned* __restrict__ hprev, const unsigned* __restrict__ hpool,
    float* __restrict__ c2, unsigned* __restrict__ hout,
    unsigned short* __restrict__ p2hi, unsigned short* __restrict__ p2lo,
    const unsigned* __restrict__ h30, const unsigned* __restrict__ h31, int t)
{
    __shared__ __align__(16) unsigned short sChi[18 * 256];
    __shared__ __align__(16) unsigned short sClo[18 * 256];
    int bid = blockIdx.x;
    lstm2_body(bid & 7, (bid >> 3) & 3, bid >> 5, t,
               p1pk, w2F, b2, hprev, hpool, c2, hout, p2hi, p2lo, h30, h31,
               sChi, sClo);
}

// ---------------- final pool2 for tp=7 ----------------
__global__ void pool2(const unsigned* __restrict__ hA, const unsigned* __restrict__ hB,
                      unsigned short* __restrict__ p2hi, unsigned short* __restrict__ p2lo,
                      int tp)
{
    int idx = blockIdx.x * 256 + threadIdx.x;
    if (idx >= 8 * 48 * 2 * 64) return;
    int xp = idx & 63;
    int t1 = idx >> 6;
    int yp = t1 & 1; t1 >>= 1;
    int f = t1 % 48, b = t1 / 48;
    float m = -INFINITY;
#pragma unroll
    for (int dy = 0; dy < 2; ++dy)
#pragma unroll
        for (int dx = 0; dx < 2; ++dx) {
            int g = ((b * 48 + f) * 4 + yp * 2 + dy) * 128 + xp * 2 + dx;
            m = fmaxf(m, fmaxf(upk(hA[g]), upk(hB[g])));
        }
    int pi = ((b * 48 + f) * 16 + tp * 2 + yp) * 64 + xp;
    unsigned pm = pack_hl(m);
    p2hi[pi] = (unsigned short)pm;
    p2lo[pi] = (unsigned short)(pm >> 16);
}

// ---------------- conv3 (streaming MFMA, 3-term, K-split partials) ----------
__global__ __launch_bounds__(256) void conv3_part(
    const unsigned short* __restrict__ p2hi, const unsigned short* __restrict__ p2lo,
    const unsigned short* __restrict__ w3F,
    float* __restrict__ part)    // (12,256,112)
{
    __shared__ float sRed[4 * 7 * 256];
    const int mq = blockIdx.x, ck = blockIdx.y;
    const int tid = threadIdx.x;
    const int l = tid & 63;
    const int wv = __builtin_amdgcn_readfirstlane(tid >> 6);
    const int c = ck * 4 + wv;
    const int ln = l & 15, kg = l >> 4;

    int rowbase[7];
#pragma unroll
    for (int nt = 0; nt < 7; ++nt) {
        int col = nt * 16 + ln;
        int bi = col / 14, r = col % 14;
        rowbase[nt] = (bi * 48 + c) * 16 + r;
    }

    f32x4 acc[7];
#pragma unroll
    for (int nt = 0; nt < 7; ++nt) acc[nt] = (f32x4){0.f, 0.f, 0.f, 0.f};

#pragma unroll
    for (int kk = 0; kk < 6; ++kk) {
        int aoff = ((((mq * 48 + c) * 6 + kk) * 4 + kg) * 16 + ln) * 8;
        short8 ah = *(const short8*)&w3F[aoff];
        short8 al = *(const short8*)&w3F[PLANE_W3 + aoff];
        int s = kk * 4 + kg;
        int dr = s >> 3, w0 = (s & 7) * 8;
#pragma unroll
        for (int nt = 0; nt < 7; ++nt) {
            int boff = (rowbase[nt] + dr) * 64 + w0;
            short8 bh = *(const short8*)&p2hi[boff];
            short8 bl = *(const short8*)&p2lo[boff];
            acc[nt] = __builtin_amdgcn_mfma_f32_16x16x32_bf16(al, bh, acc[nt], 0, 0, 0);
            acc[nt] = __builtin_amdgcn_mfma_f32_16x16x32_bf16(ah, bl, acc[nt], 0, 0, 0);
            acc[nt] = __builtin_amdgcn_mfma_f32_16x16x32_bf16(ah, bh, acc[nt], 0, 0, 0);
        }
    }

#pragma unroll
    for (int nt = 0; nt < 7; ++nt)
        *(f32x4*)&sRed[wv * 1792 + nt * 256 + l * 4] = acc[nt];
    __syncthreads();

#pragma unroll
    for (int nt = 0; nt < 7; ++nt) {
        float s = sRed[nt * 256 + tid] + sRed[1792 + nt * 256 + tid] +
                  sRed[2 * 1792 + nt * 256 + tid] + sRed[3 * 1792 + nt * 256 + tid];
        int r16 = (tid >> 6) * 4 + (tid & 3);
        int m = mq * 16 + r16;
        int col = nt * 16 + ((tid >> 2) & 15);
        part[(ck * 256 + m) * 112 + col] = s;
    }
}

// ---------------- head: reduce+bias+ELU -> conv4+ELU -> conv5 ----------------
__global__ __launch_bounds__(256) void head(
    const float* __restrict__ part, const float* __restrict__ b3,
    const float* __restrict__ w4T, const float* __restrict__ b4,
    const float* __restrict__ w5T, const float* __restrict__ b5,
    float* __restrict__ out)
{
    __shared__ float sO3[256];
    __shared__ float sO4[128];
    const int col = blockIdx.x;          // b*14 + r
    const int b = col / 14, r = col % 14;
    const int tid = threadIdx.x;

    float s = b3[tid];
#pragma unroll
    for (int ck = 0; ck < 12; ++ck)
        s += part[(ck * 256 + tid) * 112 + col];
    sO3[tid] = elu(s);
    __syncthreads();

    if (tid < 128) {
        float a4 = b4[tid];
        for (int c = 0; c < 256; ++c)
            a4 = fmaf(sO3[c], w4T[c * 128 + tid], a4);
        sO4[tid] = elu(a4);
    }
    __syncthreads();

    if (tid < 88) {
        float a5 = b5[tid];
        for (int c = 0; c < 128; ++c)
            a5 = fmaf(sO4[c], w5T[c * 88 + tid], a5);
        out[(b * 88 + tid) * 14 + r] = a5;
    }
}

// ---------------- prep: weight prepacks ----------------
// w1F k-ordering: q = kk*4+kg; q<15: dy=q/5, ci=(q%5)*8+e (ci<33 else 0);
// q==15 -> 0. w2F/w3F/w4T/w5T unchanged.
__global__ void prep(const float* __restrict__ w1, const float* __restrict__ w2,
                     const float* __restrict__ w3, const float* __restrict__ w4,
                     const float* __restrict__ w5,
                     unsigned short* __restrict__ w1F, unsigned short* __restrict__ w2F,
                     unsigned short* __restrict__ w3F,
                     float* __restrict__ w4T, float* __restrict__ w5T)
{
    int i = blockIdx.x * 256 + threadIdx.x;
    if (i < 6144) {            // w1F: [dx][mt 8][kk 4][kg 4][ln 16][8]
        int base = i * 8;
        int dx = base / 16384, rem = base % 16384;
        int mt = rem / 2048, r2 = rem % 2048;
        int kk = r2 / 512, r3 = r2 % 512;
        int kg = r3 / 128, ln = (r3 % 128) / 8;
        int f = mt * 4 + (ln >> 2), gate = ln & 3;
        int co = gate * 32 + f;
        int q = kk * 4 + kg;
        short8 h;
#pragma unroll
        for (int e = 0; e < 8; ++e) {
            float v = 0.0f;
            if (q < 15) {
                int dy = q / 5, ci = (q % 5) * 8 + e;
                if (ci < 33) v = w1[co * 297 + ci * 9 + dy * 3 + dx];
            }
            h[e] = (short)bf16_rne(v);
        }
        *(short8*)&w1F[base] = h;
        return;
    }
    i -= 6144;
    if (i < 18432) {           // w2F hi: [dx][mt 12][kk 8][kg 4][ln 16][8]
        int base = i * 8;
        int dx = base / 49152, rem = base % 49152;
        int mt = rem / 4096, r2 = rem % 4096;
        int kk = r2 / 512, r3 = r2 % 512;
        int kg = r3 / 128, ln = (r3 % 128) / 8;
        int f = mt * 4 + (ln >> 2), gate = ln & 3;
        int co = gate * 48 + f;
        int k0 = kk * 32 + kg * 8;
        short8 h;
#pragma unroll
        for (int e = 0; e < 8; ++e) {
            int k = k0 + e;
            float v = (k < 240) ? w2[co * 720 + (k / 3) * 9 + (k % 3) * 3 + dx] : 0.0f;
            h[e] = (short)bf16_rne(v);
        }
        *(short8*)&w2F[base] = h;
        return;
    }
    i -= 18432;
    if (i < 294912) {          // w3F hi+lo
        int base = i * 8;
        int mq = base / 147456, rem = base % 147456;
        int c = rem / 3072, r2 = rem % 3072;
        int kk = r2 / 512, r3 = r2 % 512;
        int kg = r3 / 128, ln = (r3 % 128) / 8;
        int m = mq * 16 + ln;
        int kc0 = kk * 32 + kg * 8;
        int dr = kc0 >> 6, w0 = kc0 & 63;
        const float* src = &w3[((m * 48 + c) * 3 + dr) * 64 + w0];
        short8 hh, hl;
#pragma unroll
        for (int e = 0; e < 8; ++e) {
            float v = src[e];
            unsigned short hi = bf16_rne(v);
            hh[e] = (short)hi;
            hl[e] = (short)bf16_rne(v - bf16_to_f(hi));
        }
        *(short8*)&w3F[base] = hh;
        *(short8*)&w3F[PLANE_W3 + base] = hl;
        return;
    }
    i -= 294912;
    if (i < 32768) {           // w4 -> w4T
        int n = i / 256, cch = i % 256;
        w4T[cch * 128 + n] = w4[i];
        return;
    }
    i -= 32768;
    if (i < 11264) {           // w5 -> w5T
        int n = i / 128, cch = i % 128;
        w5T[cch * 88 + n] = w5[i];
    }
}

extern "C" void kernel_launch(void* const* d_in, const int* in_sizes, int n_in,
                              void* d_out, int out_size, void* d_ws, size_t ws_size,
                              hipStream_t stream)
{
    const float* x  = (const float*)d_in[0];
    const float* w1 = (const float*)d_in[1];
    const float* b1 = (const float*)d_in[2];
    const float* w2 = (const float*)d_in[3];
    const float* b2 = (const float*)d_in[4];
    const float* w3 = (const float*)d_in[5];
    const float* b3 = (const float*)d_in[6];
    const float* w4 = (const float*)d_in[7];
    const float* b4 = (const float*)d_in[8];
    const float* w5 = (const float*)d_in[9];
    const float* b5 = (const float*)d_in[10];
    float* out = (float*)d_out;

    float* ws = (float*)d_ws;
    size_t off = 0;
    auto alloc = [&](size_t n) { float* p = ws + off; off += n; return p; };
    unsigned* h1[4];
    h1[0] = (unsigned*)alloc(524288); h1[1] = (unsigned*)alloc(524288);
    h1[2] = (unsigned*)alloc(524288); h1[3] = (unsigned*)alloc(524288);
    float* c1[2];
    c1[0] = alloc(524288); c1[1] = alloc(524288);
    unsigned* p1pk = (unsigned*)alloc(2097152);
    unsigned* h2[3];
    h2[0] = (unsigned*)alloc(196608); h2[1] = (unsigned*)alloc(196608);
    h2[2] = (unsigned*)alloc(196608);
    float* c2 = alloc(196608);
    unsigned short* p2hi = (unsigned short*)alloc(196608);
    unsigned short* p2lo = (unsigned short*)alloc(196608);
    float* part = alloc(344064);
    unsigned short* w1F = (unsigned short*)alloc(24576);
    unsigned short* w2F = (unsigned short*)alloc(73728);
    unsigned short* w3F = (unsigned short*)alloc(2359296);
    float* w4T = alloc(32768);
    float* w5T = alloc(11264);
    (void)ws_size; (void)off;

    prep<<<1420, 256, 0, stream>>>(w1, w2, w3, w4, w5, w1F, w2F, w3F, w4T, w5T);

    for (int j = 0; j < 16; ++j) {
        int t2 = j - 2;   // embedded lstm2 step (j>=2): tp = j-2 in 0..13
        int nblk = (t2 >= 0) ? 768 : 512;
        fused_k<<<nblk, 256, 0, stream>>>(
            x, w1F, b1,
            h1[(2 * j + 3) & 3],           // hprev = h(2j-1)
            h1[(2 * j + 2) & 3],           // hA = h(2j-2)
            h1[(2 * j + 3) & 3],           // hB = h(2j-1)
            h1[(2 * j) & 3],               // hC = h(2j)
            h1[(2 * j + 1) & 3],           // hD = h(2j+1)
            c1[(j + 1) & 1], c1[j & 1],
            p1pk, w2F, b2,
            t2 >= 0 ? h2[(t2 + 2) % 3] : h2[0],
            t2 >= 0 ? h2[(t2 + 1) % 3] : h2[0],
            t2 >= 0 ? h2[t2 % 3] : h2[0],
            c2, p2hi, p2lo, j, t2);
    }

    // lstm2 tp=14: p1[14] pooled in kernel j=15; pools p2[6] internally
    lstm2_k<<<256, 256, 0, stream>>>(p1pk, w2F, b2, h2[(14 + 2) % 3], h2[(14 + 1) % 3],
                                     c2, h2[14 % 3], p2hi, p2lo, h1[0], h1[0], 14);
    // lstm2 tp=15 with pool1(tp=15) folded: h(30)=h1[2], h(31)=h1[3]
    lstm2_k<<<256, 256, 0, stream>>>(p1pk, w2F, b2, h2[(15 + 2) % 3], h2[(15 + 1) % 3],
                                     c2, h2[15 % 3], p2hi, p2lo, h1[2], h1[3], 15);
    pool2<<<192, 256, 0, stream>>>(h2[14 % 3], h2[15 % 3], p2hi, p2lo, 7); // h2(14), h2(15)

    conv3_part<<<dim3(16, 12), 256, 0, stream>>>(p2hi, p2lo, w3F, part);
    head<<<112, 256, 0, stream>>>(part, b3, w4T, b4, w5T, b5, out);
}

// Round 17
// 484.384 us; speedup vs baseline: 2.2246x; 2.2246x over previous
//
#include <hip/hip_runtime.h>
#include <math.h>

// Net: ConvLSTM(32)->pool->ConvLSTM(48)->pool->conv3+ELU->conv4(1x1)+ELU->conv5(1x1)
// B=8, T=32, H=8, W=256, F1=32, F2=48, F3=256, F4=128, NNOTE=88
// R17 = R13 (best verified, 484us). Per-step MFMA kernels; lstm2 embedded in
// lstm1 launches (dep-offset co-scheduling); packed bf16 hi/lo state; fused
// pools. Pair-fusion (R12/R16) and persistent grid-barrier (R8) both measured
// worse: halo overfetch / LDS conflicts / cross-XCD fence costs exceed the
// ~10us/launch they save. 37 launches.

#define DEVINL static __device__ __forceinline__
typedef __attribute__((ext_vector_type(8))) short short8;
typedef __attribute__((ext_vector_type(4))) float f32x4;

#define PLANE_W3 2359296

DEVINL float sigm(float x) { return 1.0f / (1.0f + __expf(-x)); }
DEVINL float tanh_fast(float x) { return 1.0f - 2.0f / (__expf(2.0f * x) + 1.0f); }
DEVINL float elu(float x) { return x > 0.0f ? x : expm1f(x); }
DEVINL unsigned short bf16_rne(float v) {
    unsigned u = __float_as_uint(v);
    unsigned r = (u + 0x7FFF + ((u >> 16) & 1)) >> 16;
    return (unsigned short)r;
}
DEVINL float bf16_to_f(unsigned short h) { return __uint_as_float(((unsigned)h) << 16); }
DEVINL unsigned pack_hl(float v) {
    unsigned short hi = bf16_rne(v);
    unsigned short lo = bf16_rne(v - bf16_to_f(hi));
    return (unsigned)hi | ((unsigned)lo << 16);
}
DEVINL float upk(unsigned u) {
    return __uint_as_float(u << 16) + __uint_as_float(u & 0xffff0000u);
}

// ---------------- LSTM1 step body (MFMA, 2-term split) ----------------
DEVINL void lstm1_body(
    int xq, int y, int b, int t,
    const unsigned* __restrict__ xpk, const unsigned short* __restrict__ w1F,
    const float* __restrict__ b1,
    const unsigned* __restrict__ hprev, const unsigned* __restrict__ hpool,
    unsigned* __restrict__ hout, float* __restrict__ c1,
    unsigned* __restrict__ p1pk)
{
    __shared__ __align__(16) unsigned short sBhi[34 * 128];
    __shared__ __align__(16) unsigned short sBlo[34 * 128];
    const int x0 = xq * 32;
    const int tid = threadIdx.x;

    if (((t & 1) == 0) && t >= 2 && (y & 1) == 1) {
        int tp = (t >> 1) - 1, yp = y >> 1;
        for (int e = tid; e < 512; e += 256) {
            int f = e >> 4, xl = e & 15;
            int xp = (x0 >> 1) + xl, gx = x0 + 2 * xl;
            int b0 = ((b * 32 + f) * 8 + (y - 1)) * 256 + gx;
            float m = upk(hpool[b0]);
            m = fmaxf(m, upk(hpool[b0 + 1]));
            m = fmaxf(m, upk(hpool[b0 + 256]));
            m = fmaxf(m, upk(hpool[b0 + 257]));
            m = fmaxf(m, upk(hprev[b0]));
            m = fmaxf(m, upk(hprev[b0 + 1]));
            m = fmaxf(m, upk(hprev[b0 + 256]));
            m = fmaxf(m, upk(hprev[b0 + 257]));
            p1pk[(((b * 32 + f) * 16 + tp) * 4 + yp) * 128 + xp] = pack_hl(m);
        }
    }

    for (int e = tid; e < 34 * 128; e += 256) {
        int lx = e % 34, kk = e / 34;
        unsigned u = 0;
        if (kk < 99) {
            int ci = kk / 3, dy = kk - ci * 3;
            int gy = y + dy - 1, gx = x0 + lx - 1;
            if (gy >= 0 && gy < 8 && gx >= 0 && gx < 256)
                u = (ci == 0) ? xpk[((b * 32 + t) * 8 + gy) * 256 + gx]
                              : hprev[((b * 32 + (ci - 1)) * 8 + gy) * 256 + gx];
        }
        int a16 = lx * 128 + (((kk >> 3) ^ (lx & 15)) << 3) + (kk & 7);
        sBhi[a16] = (unsigned short)u;
        sBlo[a16] = (unsigned short)(u >> 16);
    }
    __syncthreads();

    const int l = tid & 63;
    const int wv = __builtin_amdgcn_readfirstlane(tid >> 6);
    const int ln = l & 15, kg = l >> 4;
    f32x4 acc[2][2];
#pragma unroll
    for (int i = 0; i < 2; ++i)
#pragma unroll
        for (int j = 0; j < 2; ++j) acc[i][j] = (f32x4){0.f, 0.f, 0.f, 0.f};

#pragma unroll
    for (int kk = 0; kk < 4; ++kk) {
        short8 bh[2][3], bl[2][3];
#pragma unroll
        for (int ntl = 0; ntl < 2; ++ntl)
#pragma unroll
            for (int dx = 0; dx < 3; ++dx) {
                int lx = ntl * 16 + ln + dx;
                int slot = kk * 4 + kg;
                int boff = lx * 128 + ((slot ^ (lx & 15)) << 3);
                bh[ntl][dx] = *(const short8*)&sBhi[boff];
                bl[ntl][dx] = *(const short8*)&sBlo[boff];
            }
#pragma unroll
        for (int mtl = 0; mtl < 2; ++mtl)
#pragma unroll
            for (int dx = 0; dx < 3; ++dx) {
                int aoff = ((((dx * 8 + wv * 2 + mtl) * 4 + kk) * 4 + kg) * 16 + ln) * 8;
                short8 ah = *(const short8*)&w1F[aoff];
#pragma unroll
                for (int ntl = 0; ntl < 2; ++ntl) {
                    acc[mtl][ntl] = __builtin_amdgcn_mfma_f32_16x16x32_bf16(ah, bl[ntl][dx], acc[mtl][ntl], 0, 0, 0);
                    acc[mtl][ntl] = __builtin_amdgcn_mfma_f32_16x16x32_bf16(ah, bh[ntl][dx], acc[mtl][ntl], 0, 0, 0);
                }
            }
    }

#pragma unroll
    for (int mtl = 0; mtl < 2; ++mtl) {
        const int f = (wv * 2 + mtl) * 4 + kg;
        const float bi = b1[f], bff = b1[32 + f], bg = b1[64 + f], bo = b1[96 + f];
#pragma unroll
        for (int ntl = 0; ntl < 2; ++ntl) {
            f32x4 a = acc[mtl][ntl];
            int gidx = ((b * 32 + f) * 8 + y) * 256 + x0 + ntl * 16 + ln;
            float zi = a[0] + bi, zf = a[1] + bff, zg = a[2] + bg, zo = a[3] + bo;
            float cv = c1[gidx];
            float cn = sigm(zf) * cv + sigm(zi) * tanh_fast(zg);
            c1[gidx] = cn;
            hout[gidx] = pack_hl(sigm(zo) * tanh_fast(cn));
        }
    }
}

// ---------------- LSTM2 step body ----------------
// t==15: ci<32 staging pools on the fly from h30/h31 (pool1k folded in).
DEVINL void lstm2_body(
    int xq, int y, int b, int t,
    const unsigned* __restrict__ p1pk, const unsigned short* __restrict__ w2F,
    const float* __restrict__ b2,
    const unsigned* __restrict__ hprev, const unsigned* __restrict__ hpool,
    float* __restrict__ c2, unsigned* __restrict__ hout,
    unsigned short* __restrict__ p2hi, unsigned short* __restrict__ p2lo,
    const unsigned* __restrict__ h30, const unsigned* __restrict__ h31)
{
    __shared__ __align__(16) unsigned short sChi[18 * 256];
    __shared__ __align__(16) unsigned short sClo[18 * 256];
    const int x0 = xq * 16;
    const int tid = threadIdx.x;

    if (((t & 1) == 0) && t >= 2 && y < 2) {
        int tp = (t >> 1) - 1;
        for (int e = tid; e < 48 * 8; e += 256) {
            int f = e >> 3, xl = e & 7;
            int xp = xq * 8 + xl;
            int g0 = ((b * 48 + f) * 4 + y * 2) * 128 + xp * 2;
            float m = fmaxf(fmaxf(upk(hpool[g0]), upk(hpool[g0 + 1])),
                            fmaxf(upk(hpool[g0 + 128]), upk(hpool[g0 + 129])));
            m = fmaxf(m, fmaxf(fmaxf(upk(hprev[g0]), upk(hprev[g0 + 1])),
                               fmaxf(upk(hprev[g0 + 128]), upk(hprev[g0 + 129]))));
            int pi = ((b * 48 + f) * 16 + tp * 2 + y) * 64 + xp;
            unsigned pm = pack_hl(m);
            p2hi[pi] = (unsigned short)pm;
            p2lo[pi] = (unsigned short)(pm >> 16);
        }
    }

    for (int idx = tid; idx < 80 * 54; idx += 256) {
        int ci = idx / 54, rem = idx % 54;
        int dy = rem / 18, lx = rem % 18;
        int gy = y + dy - 1, gx = x0 + lx - 1;
        unsigned u = 0;
        if (gy >= 0 && gy < 4 && gx >= 0 && gx < 128) {
            if (ci < 32) {
                if (t == 15) {
                    // fold pool1k(tp=15): pool pair (h30,h31) at (2gy,2gx) 2x2
                    int b0 = ((b * 32 + ci) * 8 + gy * 2) * 256 + gx * 2;
                    float m = upk(h30[b0]);
                    m = fmaxf(m, upk(h30[b0 + 1]));
                    m = fmaxf(m, upk(h30[b0 + 256]));
                    m = fmaxf(m, upk(h30[b0 + 257]));
                    m = fmaxf(m, upk(h31[b0]));
                    m = fmaxf(m, upk(h31[b0 + 1]));
                    m = fmaxf(m, upk(h31[b0 + 256]));
                    m = fmaxf(m, upk(h31[b0 + 257]));
                    u = pack_hl(m);
                } else {
                    u = p1pk[(((b * 32 + ci) * 16 + t) * 4 + gy) * 128 + gx];
                }
            } else {
                u = hprev[((b * 48 + (ci - 32)) * 4 + gy) * 128 + gx];
            }
        }
        int k = ci * 3 + dy;
        int a16 = lx * 256 + (((k >> 3) ^ (lx & 15)) << 3) + (k & 7);
        sChi[a16] = (unsigned short)u;
        sClo[a16] = (unsigned short)(u >> 16);
    }
    // zero pad slots (k = 240..255)
    for (int e = tid; e < 18 * 16; e += 256) {
        int lx = e >> 4, k = 240 + (e & 15);
        int a16 = lx * 256 + (((k >> 3) ^ (lx & 15)) << 3) + (k & 7);
        sChi[a16] = 0;
        sClo[a16] = 0;
    }
    __syncthreads();

    const int l = tid & 63;
    const int wv = __builtin_amdgcn_readfirstlane(tid >> 6);
    const int ln = l & 15, kg = l >> 4;
    f32x4 acc[3] = {{0.f,0.f,0.f,0.f},{0.f,0.f,0.f,0.f},{0.f,0.f,0.f,0.f}};

#pragma unroll
    for (int kk = 0; kk < 8; ++kk) {
        short8 bh[3], bl[3];
#pragma unroll
        for (int dx = 0; dx < 3; ++dx) {
            int lx = ln + dx;
            int boff = lx * 256 + ((((kk << 2) + kg) ^ (lx & 15)) << 3);
            bh[dx] = *(const short8*)&sChi[boff];
            bl[dx] = *(const short8*)&sClo[boff];
        }
#pragma unroll
        for (int j = 0; j < 3; ++j) {
            int mt = wv * 3 + j;
#pragma unroll
            for (int dx = 0; dx < 3; ++dx) {
                int aoff = ((((dx * 12 + mt) * 8 + kk) * 4 + kg) * 16 + ln) * 8;
                short8 ah = *(const short8*)&w2F[aoff];
                acc[j] = __builtin_amdgcn_mfma_f32_16x16x32_bf16(ah, bl[dx], acc[j], 0, 0, 0);
                acc[j] = __builtin_amdgcn_mfma_f32_16x16x32_bf16(ah, bh[dx], acc[j], 0, 0, 0);
            }
        }
    }

    const int x = x0 + ln;
#pragma unroll
    for (int j = 0; j < 3; ++j) {
        int mt = wv * 3 + j;
        int f = mt * 4 + kg;
        float zi = acc[j][0] + b2[f];
        float zf = acc[j][1] + b2[48 + f];
        float zg = acc[j][2] + b2[96 + f];
        float zo = acc[j][3] + b2[144 + f];
        int gidx = ((b * 48 + f) * 4 + y) * 128 + x;
        float cv = c2[gidx];
        float cn = sigm(zf) * cv + sigm(zi) * tanh_fast(zg);
        c2[gidx] = cn;
        hout[gidx] = pack_hl(sigm(zo) * tanh_fast(cn));
    }
}

// ---------------- combined step kernel ----------------
__global__ __launch_bounds__(256) void step_k(
    const unsigned* __restrict__ xpk, const unsigned short* __restrict__ w1F,
    const float* __restrict__ b1,
    const unsigned* __restrict__ hprev1, const unsigned* __restrict__ hpool1,
    unsigned* __restrict__ hout1, float* __restrict__ c1,
    unsigned* __restrict__ p1pk,
    const unsigned short* __restrict__ w2F, const float* __restrict__ b2,
    const unsigned* __restrict__ hprev2, const unsigned* __restrict__ hpool2,
    unsigned* __restrict__ hout2, float* __restrict__ c2,
    unsigned short* __restrict__ p2hi, unsigned short* __restrict__ p2lo,
    int t, int t2)
{
    int bid = blockIdx.x;
    if (gridDim.x == 768) {
        if (bid < 256) {
            lstm2_body(bid & 7, (bid >> 3) & 3, bid >> 5, t2,
                       p1pk, w2F, b2, hprev2, hpool2, c2, hout2, p2hi, p2lo,
                       hout1, hout1);
            return;
        }
        bid -= 256;
    }
    lstm1_body(bid & 7, (bid >> 3) & 7, bid >> 6, t,
               xpk, w1F, b1, hprev1, hpool1, hout1, c1, p1pk);
}

// ---------------- standalone lstm2 (tp=15, pool1 fused) ----------------
__global__ __launch_bounds__(256) void lstm2_k(
    const unsigned* __restrict__ p1pk, const unsigned short* __restrict__ w2F,
    const float* __restrict__ b2,
    const unsigned* __restrict__ hprev, const unsigned* __restrict__ hpool,
    float* __restrict__ c2, unsigned* __restrict__ hout,
    unsigned short* __restrict__ p2hi, unsigned short* __restrict__ p2lo,
    const unsigned* __restrict__ h30, const unsigned* __restrict__ h31, int t)
{
    int bid = blockIdx.x;
    lstm2_body(bid & 7, (bid >> 3) & 3, bid >> 5, t,
               p1pk, w2F, b2, hprev, hpool, c2, hout, p2hi, p2lo, h30, h31);
}

// ---------------- final pool2 for tp=7 ----------------
__global__ void pool2(const unsigned* __restrict__ hA, const unsigned* __restrict__ hB,
                      unsigned short* __restrict__ p2hi, unsigned short* __restrict__ p2lo,
                      int tp)
{
    int idx = blockIdx.x * 256 + threadIdx.x;
    if (idx >= 8 * 48 * 2 * 64) return;
    int xp = idx & 63;
    int t1 = idx >> 6;
    int yp = t1 & 1; t1 >>= 1;
    int f = t1 % 48, b = t1 / 48;
    float m = -INFINITY;
#pragma unroll
    for (int dy = 0; dy < 2; ++dy)
#pragma unroll
        for (int dx = 0; dx < 2; ++dx) {
            int g = ((b * 48 + f) * 4 + yp * 2 + dy) * 128 + xp * 2 + dx;
            m = fmaxf(m, fmaxf(upk(hA[g]), upk(hB[g])));
        }
    int pi = ((b * 48 + f) * 16 + tp * 2 + yp) * 64 + xp;
    unsigned pm = pack_hl(m);
    p2hi[pi] = (unsigned short)pm;
    p2lo[pi] = (unsigned short)(pm >> 16);
}

// ---------------- conv3 (streaming MFMA, 3-term, K-split partials) ----------
__global__ __launch_bounds__(256) void conv3_part(
    const unsigned short* __restrict__ p2hi, const unsigned short* __restrict__ p2lo,
    const unsigned short* __restrict__ w3F,
    float* __restrict__ part)    // (12,256,112)
{
    __shared__ float sRed[4 * 7 * 256];
    const int mq = blockIdx.x, ck = blockIdx.y;
    const int tid = threadIdx.x;
    const int l = tid & 63;
    const int wv = __builtin_amdgcn_readfirstlane(tid >> 6);
    const int c = ck * 4 + wv;
    const int ln = l & 15, kg = l >> 4;

    int rowbase[7];
#pragma unroll
    for (int nt = 0; nt < 7; ++nt) {
        int col = nt * 16 + ln;
        int bi = col / 14, r = col % 14;
        rowbase[nt] = (bi * 48 + c) * 16 + r;
    }

    f32x4 acc[7];
#pragma unroll
    for (int nt = 0; nt < 7; ++nt) acc[nt] = (f32x4){0.f, 0.f, 0.f, 0.f};

#pragma unroll
    for (int kk = 0; kk < 6; ++kk) {
        int aoff = ((((mq * 48 + c) * 6 + kk) * 4 + kg) * 16 + ln) * 8;
        short8 ah = *(const short8*)&w3F[aoff];
        short8 al = *(const short8*)&w3F[PLANE_W3 + aoff];
        int s = kk * 4 + kg;
        int dr = s >> 3, w0 = (s & 7) * 8;
#pragma unroll
        for (int nt = 0; nt < 7; ++nt) {
            int boff = (rowbase[nt] + dr) * 64 + w0;
            short8 bh = *(const short8*)&p2hi[boff];
            short8 bl = *(const short8*)&p2lo[boff];
            acc[nt] = __builtin_amdgcn_mfma_f32_16x16x32_bf16(al, bh, acc[nt], 0, 0, 0);
            acc[nt] = __builtin_amdgcn_mfma_f32_16x16x32_bf16(ah, bl, acc[nt], 0, 0, 0);
            acc[nt] = __builtin_amdgcn_mfma_f32_16x16x32_bf16(ah, bh, acc[nt], 0, 0, 0);
        }
    }

#pragma unroll
    for (int nt = 0; nt < 7; ++nt)
        *(f32x4*)&sRed[wv * 1792 + nt * 256 + l * 4] = acc[nt];
    __syncthreads();

#pragma unroll
    for (int nt = 0; nt < 7; ++nt) {
        float s = sRed[nt * 256 + tid] + sRed[1792 + nt * 256 + tid] +
                  sRed[2 * 1792 + nt * 256 + tid] + sRed[3 * 1792 + nt * 256 + tid];
        int r16 = (tid >> 6) * 4 + (tid & 3);
        int m = mq * 16 + r16;
        int col = nt * 16 + ((tid >> 2) & 15);
        part[(ck * 256 + m) * 112 + col] = s;
    }
}

// ---------------- head: reduce+bias+ELU -> conv4+ELU -> conv5 ----------------
__global__ __launch_bounds__(256) void head(
    const float* __restrict__ part, const float* __restrict__ b3,
    const float* __restrict__ w4T, const float* __restrict__ b4,
    const float* __restrict__ w5T, const float* __restrict__ b5,
    float* __restrict__ out)
{
    __shared__ float sO3[256];
    __shared__ float sO4[128];
    const int col = blockIdx.x;          // b*14 + r
    const int b = col / 14, r = col % 14;
    const int tid = threadIdx.x;

    float s = b3[tid];
#pragma unroll
    for (int ck = 0; ck < 12; ++ck)
        s += part[(ck * 256 + tid) * 112 + col];
    sO3[tid] = elu(s);
    __syncthreads();

    if (tid < 128) {
        float a4 = b4[tid];
        for (int c = 0; c < 256; ++c)
            a4 = fmaf(sO3[c], w4T[c * 128 + tid], a4);
        sO4[tid] = elu(a4);
    }
    __syncthreads();

    if (tid < 88) {
        float a5 = b5[tid];
        for (int c = 0; c < 128; ++c)
            a5 = fmaf(sO4[c], w5T[c * 88 + tid], a5);
        out[(b * 88 + tid) * 14 + r] = a5;
    }
}

// ---------------- prep: zero-init + x pack + weight prepacks ----------------
__global__ void prep(const float* __restrict__ x, const float* __restrict__ w1,
                     const float* __restrict__ w2, const float* __restrict__ w3,
                     const float* __restrict__ w4, const float* __restrict__ w5,
                     unsigned* __restrict__ zeroA,  // h1[2]+c1, 1048576 u32
                     unsigned* __restrict__ zeroB,  // h2[2]+c2, 393216 u32
                     unsigned* __restrict__ xpk,
                     unsigned short* __restrict__ w1F, unsigned short* __restrict__ w2F,
                     unsigned short* __restrict__ w3F,
                     float* __restrict__ w4T, float* __restrict__ w5T)
{
    int i = blockIdx.x * 256 + threadIdx.x;
    if (i < 65536) {
        uint4 z = {0, 0, 0, 0};
        uint4* p = (uint4*)&zeroA[i * 16];
        p[0] = z; p[1] = z; p[2] = z; p[3] = z;
        return;
    }
    i -= 65536;
    if (i < 24576) {
        uint4 z = {0, 0, 0, 0};
        uint4* p = (uint4*)&zeroB[i * 16];
        p[0] = z; p[1] = z; p[2] = z; p[3] = z;
        return;
    }
    i -= 24576;
    if (i < 131072) {
        const float4 v = *(const float4*)&x[i * 4];
        uint4 o;
        o.x = pack_hl(v.x); o.y = pack_hl(v.y);
        o.z = pack_hl(v.z); o.w = pack_hl(v.w);
        *(uint4*)&xpk[i * 4] = o;
        return;
    }
    i -= 131072;
    if (i < 6144) {
        int base = i * 8;
        int dx = base / 16384, rem = base % 16384;
        int mt = rem / 2048, r2 = rem % 2048;
        int kk = r2 / 512, r3 = r2 % 512;
        int kg = r3 / 128, ln = (r3 % 128) / 8;
        int f = mt * 4 + (ln >> 2), gate = ln & 3;
        int co = gate * 32 + f;
        int k0 = kk * 32 + kg * 8;
        short8 h;
#pragma unroll
        for (int e = 0; e < 8; ++e) {
            int k = k0 + e;
            float v = (k < 99) ? w1[co * 297 + (k / 3) * 9 + (k % 3) * 3 + dx] : 0.0f;
            h[e] = (short)bf16_rne(v);
        }
        *(short8*)&w1F[base] = h;
        return;
    }
    i -= 6144;
    if (i < 18432) {
        int base = i * 8;
        int dx = base / 49152, rem = base % 49152;
        int mt = rem / 4096, r2 = rem % 4096;
        int kk = r2 / 512, r3 = r2 % 512;
        int kg = r3 / 128, ln = (r3 % 128) / 8;
        int f = mt * 4 + (ln >> 2), gate = ln & 3;
        int co = gate * 48 + f;
        int k0 = kk * 32 + kg * 8;
        short8 h;
#pragma unroll
        for (int e = 0; e < 8; ++e) {
            int k = k0 + e;
            float v = (k < 240) ? w2[co * 720 + (k / 3) * 9 + (k % 3) * 3 + dx] : 0.0f;
            h[e] = (short)bf16_rne(v);
        }
        *(short8*)&w2F[base] = h;
        return;
    }
    i -= 18432;
    if (i < 294912) {
        int base = i * 8;
        int mq = base / 147456, rem = base % 147456;
        int c = rem / 3072, r2 = rem % 3072;
        int kk = r2 / 512, r3 = r2 % 512;
        int kg = r3 / 128, ln = (r3 % 128) / 8;
        int m = mq * 16 + ln;
        int kc0 = kk * 32 + kg * 8;
        int dr = kc0 >> 6, w0 = kc0 & 63;
        const float* src = &w3[((m * 48 + c) * 3 + dr) * 64 + w0];
        short8 hh, hl;
#pragma unroll
        for (int e = 0; e < 8; ++e) {
            float v = src[e];
            unsigned short hi = bf16_rne(v);
            hh[e] = (short)hi;
            hl[e] = (short)bf16_rne(v - bf16_to_f(hi));
        }
        *(short8*)&w3F[base] = hh;
        *(short8*)&w3F[PLANE_W3 + base] = hl;
        return;
    }
    i -= 294912;
    if (i < 32768) {
        int n = i / 256, cch = i % 256;
        w4T[cch * 128 + n] = w4[i];
        return;
    }
    i -= 32768;
    if (i < 11264) {
        int n = i / 128, cch = i % 128;
        w5T[cch * 88 + n] = w5[i];
    }
}

extern "C" void kernel_launch(void* const* d_in, const int* in_sizes, int n_in,
                              void* d_out, int out_size, void* d_ws, size_t ws_size,
                              hipStream_t stream)
{
    const float* x  = (const float*)d_in[0];
    const float* w1 = (const float*)d_in[1];
    const float* b1 = (const float*)d_in[2];
    const float* w2 = (const float*)d_in[3];
    const float* b2 = (const float*)d_in[4];
    const float* w3 = (const float*)d_in[5];
    const float* b3 = (const float*)d_in[6];
    const float* w4 = (const float*)d_in[7];
    const float* b4 = (const float*)d_in[8];
    const float* w5 = (const float*)d_in[9];
    const float* b5 = (const float*)d_in[10];
    float* out = (float*)d_out;

    float* ws = (float*)d_ws;
    size_t off = 0;
    auto alloc = [&](size_t n) { float* p = ws + off; off += n; return p; };
    unsigned* h1[3];
    h1[0] = (unsigned*)alloc(524288); h1[1] = (unsigned*)alloc(524288);
    h1[2] = (unsigned*)alloc(524288);
    float* c1 = alloc(524288);        // contiguous after h1[2] -> zeroA
    unsigned* xpk = (unsigned*)alloc(524288);
    unsigned* p1pk = (unsigned*)alloc(2097152);
    unsigned* h2[3];
    h2[0] = (unsigned*)alloc(196608); h2[1] = (unsigned*)alloc(196608);
    h2[2] = (unsigned*)alloc(196608);
    float* c2 = alloc(196608);        // contiguous after h2[2] -> zeroB
    unsigned short* p2hi = (unsigned short*)alloc(196608);
    unsigned short* p2lo = (unsigned short*)alloc(196608);
    float* part = alloc(344064);
    unsigned short* w1F = (unsigned short*)alloc(24576);
    unsigned short* w2F = (unsigned short*)alloc(73728);
    unsigned short* w3F = (unsigned short*)alloc(2359296);
    float* w4T = alloc(32768);
    float* w5T = alloc(11264);
    (void)ws_size; (void)off;

    prep<<<2284, 256, 0, stream>>>(x, w1, w2, w3, w4, w5,
                                   h1[2], h2[2], xpk, w1F, w2F, w3F, w4T, w5T);

    for (int t = 0; t < 32; ++t) {
        // embedded lstm2 timestep: even t >= 4 -> tp=(t-4)/2 (0..13); t=31 -> 14
        int t2 = ((t & 1) == 0 && t >= 4) ? (t - 4) / 2 : (t == 31 ? 14 : -1);
        int nblk = (t2 >= 0) ? 768 : 512;
        step_k<<<nblk, 256, 0, stream>>>(
            xpk, w1F, b1, h1[(t + 2) % 3], h1[(t + 1) % 3], h1[t % 3], c1, p1pk,
            w2F, b2,
            t2 >= 0 ? h2[(t2 + 2) % 3] : h2[0],
            t2 >= 0 ? h2[(t2 + 1) % 3] : h2[0],
            t2 >= 0 ? h2[t2 % 3] : h2[0],
            c2, p2hi, p2lo, t, t2);
    }

    // lstm2 tp=15 with pool1(tp=15) fused: h(30)=h1[0], h(31)=h1[1]
    lstm2_k<<<256, 256, 0, stream>>>(p1pk, w2F, b2, h2[2], h2[1], c2, h2[0],
                                     p2hi, p2lo, h1[0], h1[1], 15);
    pool2<<<192, 256, 0, stream>>>(h2[2], h2[0], p2hi, p2lo, 7); // h(14), h(15)

    conv3_part<<<dim3(16, 12), 256, 0, stream>>>(p2hi, p2lo, w3F, part);
    head<<<112, 256, 0, stream>>>(part, b3, w4T, b4, w5T, b5, out);
}